// Round 12
// baseline (517.577 us; speedup 1.0000x reference)
//
#include <hip/hip_runtime.h>
#include <stdint.h>

// ---------- types & helpers ----------
typedef __attribute__((ext_vector_type(8))) short v8s;   // 8 x bf16 (4 VGPRs)
typedef __attribute__((ext_vector_type(4))) float v4f;   // MFMA C/D frag

__device__ __forceinline__ uint16_t f2bf(float x){
  uint32_t u = __float_as_uint(x);
  return (uint16_t)((u + 0x7FFFu + ((u >> 16) & 1u)) >> 16);  // RNE
}
__device__ __forceinline__ uint32_t pk2(float a, float b){
  return (uint32_t)f2bf(a) | ((uint32_t)f2bf(b) << 16);
}

// async global->LDS, 16B per lane. LDS dest is wave-uniform-base + lane*16 (linear).
__device__ __forceinline__ void gl16(const uint16_t* g, uint16_t* l){
  __builtin_amdgcn_global_load_lds((const __attribute__((address_space(1))) void*)g,
                                   (__attribute__((address_space(3))) void*)l, 16, 0, 0);
}

// ---------- prep kernels ----------
__global__ void __launch_bounds__(256) dra_cvt(const float* __restrict__ s,
                                               uint16_t* __restrict__ d, int n8){
  int i = blockIdx.x * 256 + threadIdx.x;
  if (i >= n8) return;
  const float4* sp = (const float4*)(s + (size_t)i * 8);
  float4 f0 = sp[0], f1 = sp[1];
  uint4 u; u.x = pk2(f0.x, f0.y); u.y = pk2(f0.z, f0.w);
  u.z = pk2(f1.x, f1.y); u.w = pk2(f1.z, f1.w);
  *(uint4*)(d + (size_t)i * 8) = u;
}

// dst[c][r] = src[r][c], dst bf16 [C][R]
__global__ void __launch_bounds__(256) dra_tcvt(const float* __restrict__ s,
                                                uint16_t* __restrict__ d, int R, int C){
  int r8 = R >> 3;
  int id = blockIdx.x * 256 + threadIdx.x;
  if (id >= C * r8) return;
  int c = id / r8, r0 = (id - c * r8) * 8;
  float v[8];
  #pragma unroll
  for (int e = 0; e < 8; e++) v[e] = s[(size_t)(r0 + e) * C + c];
  uint4 u; u.x = pk2(v[0], v[1]); u.y = pk2(v[2], v[3]);
  u.z = pk2(v[4], v[5]); u.w = pk2(v[6], v[7]);
  *(uint4*)(d + (size_t)c * R + r0) = u;
}

// decoder transpose+cvt: dec [b][512 ci][12544 pos] f32 -> decT [b][12544 pos][512 ci] bf16
__global__ void __launch_bounds__(256) dra_tdec(const float* __restrict__ dec,
                                                uint16_t* __restrict__ decT){
  __shared__ uint16_t lt[64 * 80];              // [pos][ci], rowstride 80 (16B-aligned, bank-rotating)
  int t = threadIdx.x;
  int pos0 = blockIdx.x * 64;
  int ci0  = blockIdx.y * 64;
  int b    = blockIdx.z;
  #pragma unroll
  for (int i = 0; i < 4; i++){
    int idx = t + i * 256;
    int ci_l = idx >> 4, p4 = (idx & 15) * 4;
    const float4 f = *(const float4*)(dec + ((size_t)(b * 512 + ci0 + ci_l)) * 12544 + pos0 + p4);
    lt[(p4 + 0) * 80 + ci_l] = f2bf(f.x);
    lt[(p4 + 1) * 80 + ci_l] = f2bf(f.y);
    lt[(p4 + 2) * 80 + ci_l] = f2bf(f.z);
    lt[(p4 + 3) * 80 + ci_l] = f2bf(f.w);
  }
  __syncthreads();
  #pragma unroll
  for (int i = 0; i < 2; i++){
    int idx = t + i * 256;
    int p_l = idx >> 3, u = idx & 7;
    uint4 v = *(const uint4*)&lt[p_l * 80 + u * 8];
    *(uint4*)(decT + ((size_t)b * 12544 + pos0 + p_l) * 512 + ci0 + u * 8) = v;
  }
}

// pe_w [co][ci][ky][kx] f32 -> wpe2 [co][ pix*512 + ci ] bf16   (pix = ky*8+kx)
__global__ void __launch_bounds__(256) dra_wpe2(const float* __restrict__ pw,
                                                uint16_t* __restrict__ w2){
  int id = blockIdx.x * 256 + threadIdx.x;
  if (id >= 2097152) return;
  int co = id >> 12, rem = id & 4095;
  int ci8 = rem >> 6, pix = rem & 63;
  const float* s = pw + (size_t)co * 32768 + ci8 * 512 + pix;   // ci=ci8*8+j at s[j*64]
  float v[8];
  #pragma unroll
  for (int j = 0; j < 8; j++) v[j] = s[j * 64];
  uint4 u; u.x = pk2(v[0], v[1]); u.y = pk2(v[2], v[3]);
  u.z = pk2(v[4], v[5]); u.w = pk2(v[6], v[7]);
  *(uint4*)(w2 + (size_t)co * 32768 + pix * 512 + ci8 * 8) = u;
}

// trans [8][196][768] f32 -> transb [8][224][768] bf16 (pad rows = 0)
__global__ void __launch_bounds__(256) dra_transb(const float* __restrict__ tr,
                                                  uint16_t* __restrict__ d){
  int id = blockIdx.x * 256 + threadIdx.x;
  if (id >= 1792 * 96) return;
  int n = id / 96, e0 = (id - n * 96) * 8;
  int b = n / 224, nl = n - b * 224;
  uint4 u = {0u,0u,0u,0u};
  if (nl < 196){
    const float* sp = tr + ((size_t)(b * 196 + nl)) * 768 + e0;
    u.x = pk2(sp[0], sp[1]); u.y = pk2(sp[2], sp[3]);
    u.z = pk2(sp[4], sp[5]); u.w = pk2(sp[6], sp[7]);
  }
  *(uint4*)(d + (size_t)n * 768 + e0) = u;
}

// fold conv bias + BN into per-channel scale/shift
__global__ void dra_scales(const float* mcb, const float* g1, const float* b1,
                           const float* m1, const float* v1,
                           const float* rcb, const float* g2, const float* b2,
                           const float* m2, const float* v2,
                           float* s1, float* o1, float* s2, float* o2){
  int i = blockIdx.x * 256 + threadIdx.x;
  if (i >= 512) return;
  float sc1 = g1[i] / sqrtf(v1[i] + 1e-3f);
  s1[i] = sc1; o1[i] = (mcb[i] - m1[i]) * sc1 + b1[i];
  float sc2 = g2[i] / sqrtf(v2[i] + 1e-3f);
  s2[i] = sc2; o2[i] = (rcb[i] - m2[i]) * sc2 + b2[i];
}

// ---------- K1: patch-embed split-K GEMM ----------
// A (decT tokens) -> gl16+LDS 3-buffer; B (wpe2 weights, XCD-pinned L2-resident) ->
// register-prefetch at distance 2. Per step per thread: 2 gl16 + 4 glob loads = 6 vmem ops.
// Steady-state wait = vmcnt(6) (previous step's 6 complete, current 6 in flight).
__global__ void __launch_bounds__(256, 3) dra_k1(const uint16_t* __restrict__ decT,
    const uint16_t* __restrict__ wpe2, float* __restrict__ part)
{
  __shared__ uint16_t lA[3][128 * 32];
  int t = threadIdx.x;
  int L = blockIdx.x;
  int x = L & 7, n = L >> 3;           // n in [0,112)
  int shi = n / 56, rem = n - shi * 56;
  int tok_t = rem >> 2, co_t = rem & 3;
  int s    = shi * 8 + x;              // split 0..15 pinned to xcd x
  int bco  = co_t * 128;
  int tok0 = tok_t * 128;
  int lane = t & 63, w = t >> 6;
  int wm = w >> 1, wn = w & 1;
  int lr = lane & 15, lg = lane >> 4;

  // A staging (decT gather), chunk-swizzled source
  const uint16_t* aB[2];
  #pragma unroll
  for (int i = 0; i < 2; i++){
    int u = t + i * 256;
    int row = u >> 2, h = u & 3;
    int hs = h ^ ((row >> 1) & 3);
    int token = tok0 + row;
    int b = token / 224, tl = token - b * 224;
    if (tl > 195) tl = 195;                       // clamp pad tokens
    int py = tl / 14, px = tl - py * 14;
    aB[i] = decT + ((size_t)b * 12544 + py * 896 + px * 8) * 512 + hs * 8;
  }
  // B direct: per-lane fragment pointers into wpe2 (16 rows x 64B coalesced per load)
  const uint16_t* bP[4];
  #pragma unroll
  for (int nf = 0; nf < 4; nf++)
    bP[nf] = wpe2 + (size_t)(bco + wn*64 + nf*16 + lr) * 32768 + s * 2048 + lg * 8;

  // A fragment read offsets (swizzled slots)
  int aoff[4];
  #pragma unroll
  for (int mf = 0; mf < 4; mf++){
    int R = wm*64 + mf*16 + lr;
    aoff[mf] = R * 32 + (lg ^ ((R >> 1) & 3)) * 8;
  }

  const v4f vzero = {0.f,0.f,0.f,0.f};
  v4f acc[4][4];
  #pragma unroll
  for (int i = 0; i < 4; i++)
    #pragma unroll
    for (int j = 0; j < 4; j++) acc[i][j] = vzero;

  auto stageA = [&](int kk){
    int pix = s * 4 + (kk >> 4);
    int base = ((pix >> 3) * 112 + (pix & 7)) * 512 + ((kk & 15) << 5);
    int pb = kk % 3;
    gl16(aB[0] + base, &lA[pb][t * 8]);
    gl16(aB[1] + base, &lA[pb][(t + 256) * 8]);
  };
  v8s bpf0[4], bpf1[4];
  auto loadB = [&](int kk, v8s (&bp)[4]){
    int ko = kk << 5;
    #pragma unroll
    for (int nf = 0; nf < 4; nf++) bp[nf] = *(const v8s*)(bP[nf] + ko);
  };

  stageA(0); loadB(0, bpf0);
  stageA(1); loadB(1, bpf1);
  __builtin_amdgcn_sched_barrier(0);
  asm volatile("s_waitcnt vmcnt(6)" ::: "memory");
  __builtin_amdgcn_s_barrier();
  __builtin_amdgcn_sched_barrier(0);

  auto sub = [&](int kk, v8s (&bp)[4]){
    v8s av[4], bv[4];
    #pragma unroll
    for (int mf = 0; mf < 4; mf++) av[mf] = *(const v8s*)&lA[kk % 3][aoff[mf]];
    #pragma unroll
    for (int nf = 0; nf < 4; nf++) bv[nf] = bp[nf];
    #pragma unroll
    for (int mf = 0; mf < 4; mf++)
      #pragma unroll
      for (int nf = 0; nf < 4; nf++)
        acc[mf][nf] = __builtin_amdgcn_mfma_f32_16x16x32_bf16(av[mf], bv[nf], acc[mf][nf], 0, 0, 0);
    if (kk + 2 < 64){ stageA(kk + 2); loadB(kk + 2, bp); }
    __builtin_amdgcn_sched_barrier(0);
    if (kk < 63){
      if (kk < 62) asm volatile("s_waitcnt vmcnt(6)" ::: "memory");
      else         asm volatile("s_waitcnt vmcnt(0)" ::: "memory");
      __builtin_amdgcn_s_barrier();
      __builtin_amdgcn_sched_barrier(0);
    }
  };
  for (int kk2 = 0; kk2 < 64; kk2 += 2){
    sub(kk2,     bpf0);
    sub(kk2 + 1, bpf1);
  }

  float* pd = part + (size_t)s * 917504;
  #pragma unroll
  for (int mf = 0; mf < 4; mf++){
    #pragma unroll
    for (int nf = 0; nf < 4; nf++){
      int tokg = tok0 + wm*64 + mf*16 + lg*4;
      int cog  = bco  + wn*64 + nf*16 + lr;
      #pragma unroll
      for (int r = 0; r < 4; r++)
        pd[(size_t)(tokg + r) * 512 + cog] = acc[mf][nf][r];
    }
  }
}

// reduce 16 split partials + bias -> dlb bf16 [1792][512]
__global__ void __launch_bounds__(256) dra_red(const float* __restrict__ part,
    const float* __restrict__ peb, uint16_t* __restrict__ dlb){
  int id = blockIdx.x * 256 + threadIdx.x;
  if (id >= 114688) return;
  int tok = id >> 6, c8 = (id & 63) * 8;
  float a0=0,a1=0,a2=0,a3=0,a4=0,a5=0,a6=0,a7=0;
  #pragma unroll
  for (int s = 0; s < 16; s++){
    const float* p = part + (size_t)s * 917504 + (size_t)tok * 512 + c8;
    float4 x = *(const float4*)p, y = *(const float4*)(p + 4);
    a0 += x.x; a1 += x.y; a2 += x.z; a3 += x.w;
    a4 += y.x; a5 += y.y; a6 += y.z; a7 += y.w;
  }
  const float4 b0 = *(const float4*)(peb + c8), b1 = *(const float4*)(peb + c8 + 4);
  uint4 o; o.x = pk2(a0 + b0.x, a1 + b0.y); o.y = pk2(a2 + b0.z, a3 + b0.w);
  o.z = pk2(a4 + b1.x, a5 + b1.y); o.w = pk2(a6 + b1.z, a7 + b1.w);
  *(uint4*)(dlb + (size_t)tok * 512 + c8) = o;
}

// ---------- generic NT GEMM (attention chain): D[m][n] = sum_k A[m][k]*B[n][k] ----------
template<int MREP>
__global__ void __launch_bounds__(256, 2) dra_gemm(
    const uint16_t* __restrict__ A, const uint16_t* __restrict__ Bn, void* __restrict__ Dv,
    int M, int N, int K, int lda, int ldb, int ldd,
    long long sAz, long long sBz, long long sDz,
    int epi, const float* __restrict__ svec, const float* __restrict__ ovec)
{
  constexpr int BM = MREP * 32;
  __shared__ uint16_t lA[BM * 32];
  __shared__ uint16_t lB[64 * 32];
  int t = threadIdx.x, z = blockIdx.z;
  int bm = blockIdx.x * BM, bn = blockIdx.y * 64;
  const uint16_t* Az = A + (size_t)z * sAz;
  const uint16_t* Bz = Bn + (size_t)z * sBz;
  int lane = t & 63, w = t >> 6;
  int wm = w >> 1, wn = w & 1;
  int lr = lane & 15, lg = lane >> 4;

  const uint16_t* aSrc[MREP/2]; int uuA[MREP/2];
  #pragma unroll
  for (int i = 0; i < MREP/2; i++){
    int u = t + i * 256; uuA[i] = u;
    int row = u >> 2, c = u & 3;
    int cs = c ^ ((row >> 1) & 3);
    int rg = bm + row; if (rg >= M) rg = M - 1;
    aSrc[i] = Az + (size_t)rg * lda + cs * 8;
  }
  const uint16_t* bSrc;
  {
    int row = t >> 2, c = t & 3;
    int cs = c ^ ((row >> 1) & 3);
    bSrc = Bz + (size_t)(bn + row) * ldb + cs * 8;
  }

  int aoff[MREP], boff[2];
  #pragma unroll
  for (int mf = 0; mf < MREP; mf++){
    int R = wm*(MREP*16) + mf*16 + lr;
    aoff[mf] = R * 32 + (lg ^ ((R >> 1) & 3)) * 8;
  }
  #pragma unroll
  for (int nf = 0; nf < 2; nf++){
    int R = wn*32 + nf*16 + lr;
    boff[nf] = R * 32 + (lg ^ ((R >> 1) & 3)) * 8;
  }

  const v4f vzero = {0.f, 0.f, 0.f, 0.f};
  v4f acc[MREP][2];
  #pragma unroll
  for (int i = 0; i < MREP; i++){ acc[i][0] = vzero; acc[i][1] = vzero; }

  for (int k0 = 0; k0 < K; k0 += 32){
    #pragma unroll
    for (int i = 0; i < MREP/2; i++)
      gl16(aSrc[i] + k0, &lA[uuA[i] * 8]);
    gl16(bSrc + k0, &lB[t * 8]);
    __syncthreads();
    v8s av[MREP], bv[2];
    #pragma unroll
    for (int mf = 0; mf < MREP; mf++) av[mf] = *(const v8s*)&lA[aoff[mf]];
    #pragma unroll
    for (int nf = 0; nf < 2; nf++)    bv[nf] = *(const v8s*)&lB[boff[nf]];
    #pragma unroll
    for (int mf = 0; mf < MREP; mf++)
      #pragma unroll
      for (int nf = 0; nf < 2; nf++)
        acc[mf][nf] = __builtin_amdgcn_mfma_f32_16x16x32_bf16(av[mf], bv[nf], acc[mf][nf], 0, 0, 0);
    __syncthreads();
  }

  #pragma unroll
  for (int mf = 0; mf < MREP; mf++){
    #pragma unroll
    for (int nf = 0; nf < 2; nf++){
      int mg0 = bm + wm*(MREP*16) + mf*16 + lg*4;
      int ng  = bn + wn*32 + nf*16 + lr;
      #pragma unroll
      for (int r = 0; r < 4; r++){
        int mg = mg0 + r;
        if (mg < M){
          float val = acc[mf][nf][r];
          size_t di = (size_t)z * sDz + (size_t)mg * ldd + ng;
          if (epi == 0)      ((float*)Dv)[di] = val;
          else if (epi == 1) ((uint16_t*)Dv)[di] = f2bf(val);
          else ((float*)Dv)[di] = fmaxf(val * svec[mg] + ovec[mg], 0.f);
        }
      }
    }
  }
}

// ---------- InstanceNorm stats: two-stage deterministic tree reduction ----------
__global__ void __launch_bounds__(256) dra_stats1(const float* __restrict__ sim,
                                                  double* __restrict__ ps){
  __shared__ double d1[256], d2[256];
  int b = blockIdx.y, blk = blockIdx.x, t = threadIdx.x;
  const float* s = sim + (size_t)b * 262144 + (size_t)blk * 2048 + t * 8;
  float4 x = *(const float4*)s, y = *(const float4*)(s + 4);
  double p1 = (double)x.x + x.y + x.z + x.w + y.x + y.y + y.z + y.w;
  double p2 = (double)x.x*x.x + (double)x.y*x.y + (double)x.z*x.z + (double)x.w*x.w
            + (double)y.x*y.x + (double)y.y*y.y + (double)y.z*y.z + (double)y.w*y.w;
  d1[t] = p1; d2[t] = p2;
  __syncthreads();
  for (int o = 128; o > 0; o >>= 1){
    if (t < o){ d1[t] += d1[t + o]; d2[t] += d2[t + o]; }
    __syncthreads();
  }
  if (t == 0){
    ps[(b * 128 + blk) * 2 + 0] = d1[0];
    ps[(b * 128 + blk) * 2 + 1] = d2[0];
  }
}

__global__ void __launch_bounds__(128) dra_stats2(const double* __restrict__ ps,
    const float* __restrict__ psig, const float* __restrict__ psib, float* __restrict__ ac){
  __shared__ double d1[128], d2[128];
  int b = blockIdx.x, t = threadIdx.x;
  d1[t] = ps[(b * 128 + t) * 2 + 0];
  d2[t] = ps[(b * 128 + t) * 2 + 1];
  __syncthreads();
  for (int o = 64; o > 0; o >>= 1){
    if (t < o){ d1[t] += d1[t + o]; d2[t] += d2[t + o]; }
    __syncthreads();
  }
  if (t == 0){
    double mean = d1[0] * (1.0 / 262144.0);
    double var  = d2[0] * (1.0 / 262144.0) - mean * mean;
    float a = psig[0] / (float)sqrt(var + 1e-3);
    ac[b * 2 + 0] = a;
    ac[b * 2 + 1] = psib[0] - (float)mean * a;
  }
}

// ---------- row softmax: P[b][s][t] bf16 ----------
__global__ void __launch_bounds__(256) dra_soft(const float* __restrict__ sim,
    const float* __restrict__ ac, uint16_t* __restrict__ P){
  int srow = blockIdx.x, b = blockIdx.y, t = threadIdx.x;
  const float* row = sim + (size_t)b * 262144 + (size_t)srow * 512;
  float a = ac[b * 2], c = ac[b * 2 + 1];
  float v0 = row[t] * a + c, v1 = row[t + 256] * a + c;
  __shared__ float red[256];
  red[t] = fmaxf(v0, v1);
  __syncthreads();
  for (int o = 128; o > 0; o >>= 1){
    if (t < o) red[t] = fmaxf(red[t], red[t + o]);
    __syncthreads();
  }
  float m = red[0];
  __syncthreads();
  float e0 = __expf(v0 - m), e1 = __expf(v1 - m);
  red[t] = e0 + e1;
  __syncthreads();
  for (int o = 128; o > 0; o >>= 1){
    if (t < o) red[t] += red[t + o];
    __syncthreads();
  }
  float inv = 1.f / red[0];
  uint16_t* pr = P + (size_t)b * 262144 + (size_t)srow * 512;
  pr[t] = f2bf(e0 * inv); pr[t + 256] = f2bf(e1 * inv);
}

// ---------- K3: mask conv + BN1 + ReLU, fused x recon-upsample -> out ----------
// B (decT) -> gl16+LDS 3-buffer (24KB); A (mcw, L2-resident 512KB) -> register-prefetch
// at distance 2 (16 rows x 64B coalesced). Per step per thread: 2 gl16 + 4 glob = 6 vmem.
// Steady wait vmcnt(6) + raw s_barrier: prefetch stays in flight across barriers.
__global__ void __launch_bounds__(256, 3) dra_k3(const uint16_t* __restrict__ decT,
    const uint16_t* __restrict__ mcw, const float* __restrict__ s1,
    const float* __restrict__ o1, const float* __restrict__ recon,
    float* __restrict__ outp)
{
  __shared__ uint16_t lB[3][128 * 32];
  int t = threadIdx.x;
  int L = blockIdx.x;
  int x = L & 7, n = L >> 3;          // n in [0,392)
  int co_t = n & 3, pg = n >> 2;      // pg in [0,98)
  int p = pg * 8 + x;                 // pos-tile x batch, pinned to xcd x
  int bz = p / 98, pt = p - bz * 98;
  int bco  = co_t * 128;
  int pos0 = pt * 128;
  int lane = t & 63, w = t >> 6;
  int wm = w >> 1, wn = w & 1;
  int lr = lane & 15, lg = lane >> 4;

  // B staging (decT), chunk-swizzled source
  const uint16_t* bB[2];
  #pragma unroll
  for (int i = 0; i < 2; i++){
    int u = t + i * 256;
    int row = u >> 2, h = u & 3;
    int hs = h ^ ((row >> 1) & 3);
    bB[i] = decT + ((size_t)bz * 12544 + pos0 + row) * 512 + hs * 8;
  }
  // A direct: per-lane fragment pointers into mcw
  const uint16_t* aP[4];
  #pragma unroll
  for (int mf = 0; mf < 4; mf++)
    aP[mf] = mcw + (size_t)(bco + wm*64 + mf*16 + lr) * 512 + lg * 8;

  // B fragment read offsets (swizzled slots)
  int boff[4];
  #pragma unroll
  for (int nf = 0; nf < 4; nf++){
    int R = wn*64 + nf*16 + lr;
    boff[nf] = R * 32 + (lg ^ ((R >> 1) & 3)) * 8;
  }

  const v4f vzero = {0.f,0.f,0.f,0.f};
  v4f acc[4][4];
  #pragma unroll
  for (int i = 0; i < 4; i++)
    #pragma unroll
    for (int j = 0; j < 4; j++) acc[i][j] = vzero;

  auto stageB = [&](int kk){
    int ko = kk << 5, pb = kk % 3;
    gl16(bB[0] + ko, &lB[pb][t * 8]);
    gl16(bB[1] + ko, &lB[pb][(t + 256) * 8]);
  };
  v8s apf0[4], apf1[4];
  auto loadA = [&](int kk, v8s (&ap)[4]){
    int ko = kk << 5;
    #pragma unroll
    for (int mf = 0; mf < 4; mf++) ap[mf] = *(const v8s*)(aP[mf] + ko);
  };

  stageB(0); loadA(0, apf0);
  stageB(1); loadA(1, apf1);
  __builtin_amdgcn_sched_barrier(0);
  asm volatile("s_waitcnt vmcnt(6)" ::: "memory");
  __builtin_amdgcn_s_barrier();
  __builtin_amdgcn_sched_barrier(0);

  auto sub = [&](int kk, v8s (&ap)[4]){
    v8s av[4], bv[4];
    #pragma unroll
    for (int mf = 0; mf < 4; mf++) av[mf] = ap[mf];
    #pragma unroll
    for (int nf = 0; nf < 4; nf++) bv[nf] = *(const v8s*)&lB[kk % 3][boff[nf]];
    #pragma unroll
    for (int mf = 0; mf < 4; mf++)
      #pragma unroll
      for (int nf = 0; nf < 4; nf++)
        acc[mf][nf] = __builtin_amdgcn_mfma_f32_16x16x32_bf16(av[mf], bv[nf], acc[mf][nf], 0, 0, 0);
    if (kk + 2 < 16){ stageB(kk + 2); loadA(kk + 2, ap); }
    __builtin_amdgcn_sched_barrier(0);
    if (kk < 15){
      if (kk < 14) asm volatile("s_waitcnt vmcnt(6)" ::: "memory");
      else         asm volatile("s_waitcnt vmcnt(0)" ::: "memory");
      __builtin_amdgcn_s_barrier();
      __builtin_amdgcn_sched_barrier(0);
    }
  };
  #pragma unroll
  for (int kk2 = 0; kk2 < 16; kk2 += 2){
    sub(kk2,     apf0);
    sub(kk2 + 1, apf1);
  }

  #pragma unroll
  for (int mf = 0; mf < 4; mf++){
    #pragma unroll
    for (int r = 0; r < 4; r++){
      int co = bco + wm*64 + mf*16 + lg*4 + r;
      float sc = s1[co], of = o1[co];
      const float* rrow = recon + (size_t)co * 1792 + bz * 224;
      #pragma unroll
      for (int nf = 0; nf < 4; nf++){
        int pos = pos0 + wn*64 + nf*16 + lr;
        int h = pos / 112, wd = pos - h * 112;
        int pcol = (h >> 3) * 14 + (wd >> 3);
        float mask = fmaxf(acc[mf][nf][r] * sc + of, 0.f);
        outp[((size_t)(bz * 512 + co)) * 12544 + pos] = mask * rrow[pcol];
      }
    }
  }
}

// ---------- launch ----------
extern "C" void kernel_launch(void* const* d_in, const int* in_sizes, int n_in,
                              void* d_out, int out_size, void* d_ws, size_t ws_size,
                              hipStream_t stream) {
  (void)in_sizes; (void)n_in; (void)out_size; (void)ws_size;
  const float* dec   = (const float*)d_in[0];
  const float* trans = (const float*)d_in[1];
  const float* pe_w  = (const float*)d_in[2];
  const float* pe_b  = (const float*)d_in[3];
  const float* mc_w  = (const float*)d_in[4];
  const float* mc_b  = (const float*)d_in[5];
  const float* bn1g  = (const float*)d_in[6];
  const float* bn1b  = (const float*)d_in[7];
  const float* bn1m  = (const float*)d_in[8];
  const float* bn1v  = (const float*)d_in[9];
  const float* wq    = (const float*)d_in[10];
  const float* wk    = (const float*)d_in[11];
  const float* wv    = (const float*)d_in[12];
  const float* wo    = (const float*)d_in[13];
  const float* psig  = (const float*)d_in[14];
  const float* psib  = (const float*)d_in[15];
  const float* rc_w  = (const float*)d_in[16];
  const float* rc_b  = (const float*)d_in[17];
  const float* bn2g  = (const float*)d_in[18];
  const float* bn2b  = (const float*)d_in[19];
  const float* bn2m  = (const float*)d_in[20];
  const float* bn2v  = (const float*)d_in[21];

  char* p = (char*)d_ws;
  auto take = [&](size_t bytes) -> void* {
    void* r = (void*)p; p += (bytes + 255) & ~(size_t)255; return r;
  };
  uint16_t* decT   = (uint16_t*)take((size_t)8 * 12544 * 512 * 2);   // 102.8 MB
  uint16_t* wpe2   = (uint16_t*)take((size_t)512 * 32768 * 2);       // 33.5 MB
  uint16_t* mcw    = (uint16_t*)take((size_t)512 * 512 * 2);
  uint16_t* rcw    = (uint16_t*)take((size_t)512 * 512 * 2);
  uint16_t* wqT    = (uint16_t*)take((size_t)512 * 512 * 2);
  uint16_t* woT    = (uint16_t*)take((size_t)512 * 512 * 2);
  uint16_t* wkT    = (uint16_t*)take((size_t)512 * 768 * 2);
  uint16_t* wvT    = (uint16_t*)take((size_t)512 * 768 * 2);
  uint16_t* transb = (uint16_t*)take((size_t)1792 * 768 * 2);
  float*    s1v    = (float*)take(512 * 4);
  float*    o1v    = (float*)take(512 * 4);
  float*    s2v    = (float*)take(512 * 4);
  float*    o2v    = (float*)take(512 * 4);
  uint16_t* dlb    = (uint16_t*)take((size_t)1792 * 512 * 2);
  uint16_t* Qt     = (uint16_t*)take((size_t)512 * 1792 * 2);
  uint16_t* Kt     = (uint16_t*)take((size_t)512 * 1792 * 2);
  uint16_t* Vb     = (uint16_t*)take((size_t)1792 * 512 * 2);
  float*    ac     = (float*)take(256);
  double*   ps     = (double*)take((size_t)8 * 128 * 2 * 8);         // 16 KB stats partials
  float*    part   = (float*)take((size_t)16 * 1792 * 512 * 4);      // 58.7 MB
  // alias attention temps inside part (consumed by dra_red before these are written)
  float*    simb   = part;                                            // 8.39 MB
  uint16_t* P      = (uint16_t*)(part + 2097152);                     // 4.19 MB
  uint16_t* outb   = P + 2097152;                                     // 1.84 MB
  uint16_t* out2   = outb + 917504;                                   // 1.84 MB
  float*    recon  = (float*)(out2 + 917504);                         // 3.67 MB

  // prep
  dra_tdec<<<dim3(196, 8, 8), 256, 0, stream>>>(dec, decT);
  dra_wpe2<<<8192, 256, 0, stream>>>(pe_w, wpe2);
  dra_cvt<<<128, 256, 0, stream>>>(mc_w, mcw, 32768);
  dra_cvt<<<128, 256, 0, stream>>>(rc_w, rcw, 32768);
  dra_tcvt<<<128, 256, 0, stream>>>(wq, wqT, 512, 512);
  dra_tcvt<<<192, 256, 0, stream>>>(wk, wkT, 768, 512);
  dra_tcvt<<<192, 256, 0, stream>>>(wv, wvT, 768, 512);
  dra_tcvt<<<128, 256, 0, stream>>>(wo, woT, 512, 512);
  dra_transb<<<672, 256, 0, stream>>>(trans, transb);
  dra_scales<<<2, 256, 0, stream>>>(mc_b, bn1g, bn1b, bn1m, bn1v,
                                    rc_b, bn2g, bn2b, bn2m, bn2v, s1v, o1v, s2v, o2v);

  // patch embedding: split-K partials + reduce (-> dlb bf16)
  dra_k1<<<896, 256, 0, stream>>>(decT, wpe2, part);
  dra_red<<<448, 256, 0, stream>>>(part, pe_b, dlb);

  // Qt[s][n] ; Kt[t][n] ; Vb[n][t]
  dra_gemm<2><<<dim3(8, 28, 1), 256, 0, stream>>>(wqT, dlb, Qt, 512, 1792, 512,
      512, 512, 1792, 0, 0, 0, 1, nullptr, nullptr);
  dra_gemm<2><<<dim3(8, 28, 1), 256, 0, stream>>>(wkT, transb, Kt, 512, 1792, 768,
      768, 768, 1792, 0, 0, 0, 1, nullptr, nullptr);
  dra_gemm<2><<<dim3(28, 8, 1), 256, 0, stream>>>(transb, wvT, Vb, 1792, 512, 768,
      768, 768, 512, 0, 0, 0, 1, nullptr, nullptr);

  // sim = Qt x Kt over padded tokens (zeros in pad cols of Kt)
  dra_gemm<2><<<dim3(8, 8, 8), 256, 0, stream>>>(Qt, Kt, simb, 512, 512, 224,
      1792, 1792, 512, 224, 224, 262144, 0, nullptr, nullptr);
  dra_stats1<<<dim3(128, 8), 256, 0, stream>>>(simb, ps);
  dra_stats2<<<8, 128, 0, stream>>>(ps, psig, psib, ac);
  dra_soft<<<dim3(512, 8), 256, 0, stream>>>(simb, ac, P);

  // out = P x V ; out2 = out x wo ; recon = relu(bn2(rc(out2)))
  dra_gemm<2><<<dim3(4, 8, 8), 256, 0, stream>>>(Vb, P, outb, 224, 512, 512,
      512, 512, 512, 114688, 262144, 114688, 1, nullptr, nullptr);
  dra_gemm<2><<<dim3(28, 8, 1), 256, 0, stream>>>(outb, woT, out2, 1792, 512, 512,
      512, 512, 512, 0, 0, 0, 1, nullptr, nullptr);
  dra_gemm<2><<<dim3(8, 28, 1), 256, 0, stream>>>(rcw, out2, recon, 512, 1792, 512,
      512, 512, 1792, 0, 0, 0, 2, s2v, o2v);

  // mask conv + BN1 + ReLU, x upsampled recon -> final output
  dra_k3<<<3136, 256, 0, stream>>>(decT, mcw, s1v, o1v, recon, (float*)d_out);
}

// Round 13
// 400.595 us; speedup vs baseline: 1.2920x; 1.2920x over previous
//
#include <hip/hip_runtime.h>
#include <stdint.h>

// ---------- types & helpers ----------
typedef __attribute__((ext_vector_type(8))) short v8s;   // 8 x bf16 (4 VGPRs)
typedef __attribute__((ext_vector_type(4))) float v4f;   // MFMA C/D frag

__device__ __forceinline__ uint16_t f2bf(float x){
  uint32_t u = __float_as_uint(x);
  return (uint16_t)((u + 0x7FFFu + ((u >> 16) & 1u)) >> 16);  // RNE
}
__device__ __forceinline__ uint32_t pk2(float a, float b){
  return (uint32_t)f2bf(a) | ((uint32_t)f2bf(b) << 16);
}

// async global->LDS, 16B per lane. LDS dest is wave-uniform-base + lane*16 (linear).
__device__ __forceinline__ void gl16(const uint16_t* g, uint16_t* l){
  __builtin_amdgcn_global_load_lds((const __attribute__((address_space(1))) void*)g,
                                   (__attribute__((address_space(3))) void*)l, 16, 0, 0);
}

// ---------- fused prep: one launch, block-range dispatch over 10 independent jobs ----------
// [0,12544)      tdec    : dec f32 NCHW -> decT bf16 [b][pos][ci]
// [12544,20736)  wpe2    : pe_w -> [co][pix*512+ci] bf16
// [20736,20864)  cvt mcw ; [20864,20992) cvt rcw
// [20992,21120)  tcvt wq ; [21120,21312) tcvt wk ; [21312,21504) tcvt wv ; [21504,21632) tcvt wo
// [21632,22304)  transb  ; [22304,22306) scales
__device__ __forceinline__ void prep_cvt(const float* s, uint16_t* d, int id, int n8){
  if (id >= n8) return;
  const float4* sp = (const float4*)(s + (size_t)id * 8);
  float4 f0 = sp[0], f1 = sp[1];
  uint4 u; u.x = pk2(f0.x, f0.y); u.y = pk2(f0.z, f0.w);
  u.z = pk2(f1.x, f1.y); u.w = pk2(f1.z, f1.w);
  *(uint4*)(d + (size_t)id * 8) = u;
}
__device__ __forceinline__ void prep_tcvt(const float* s, uint16_t* d, int id, int R, int C){
  int r8 = R >> 3;
  if (id >= C * r8) return;
  int c = id / r8, r0 = (id - c * r8) * 8;
  float v[8];
  #pragma unroll
  for (int e = 0; e < 8; e++) v[e] = s[(size_t)(r0 + e) * C + c];
  uint4 u; u.x = pk2(v[0], v[1]); u.y = pk2(v[2], v[3]);
  u.z = pk2(v[4], v[5]); u.w = pk2(v[6], v[7]);
  *(uint4*)(d + (size_t)c * R + r0) = u;
}

__global__ void __launch_bounds__(256) dra_prep(
    const float* __restrict__ dec, uint16_t* __restrict__ decT,
    const float* __restrict__ pw, uint16_t* __restrict__ w2,
    const float* __restrict__ mc_w, uint16_t* __restrict__ mcw,
    const float* __restrict__ rc_w, uint16_t* __restrict__ rcw,
    const float* __restrict__ wq, uint16_t* __restrict__ wqT,
    const float* __restrict__ wk, uint16_t* __restrict__ wkT,
    const float* __restrict__ wv, uint16_t* __restrict__ wvT,
    const float* __restrict__ wo, uint16_t* __restrict__ woT,
    const float* __restrict__ tr, uint16_t* __restrict__ transb,
    const float* __restrict__ mcb, const float* __restrict__ g1, const float* __restrict__ b1,
    const float* __restrict__ m1, const float* __restrict__ v1,
    const float* __restrict__ rcb, const float* __restrict__ g2, const float* __restrict__ b2,
    const float* __restrict__ m2, const float* __restrict__ v2,
    float* __restrict__ s1, float* __restrict__ o1, float* __restrict__ s2, float* __restrict__ o2)
{
  __shared__ uint16_t lt[64 * 80];
  int B = blockIdx.x, t = threadIdx.x;

  if (B < 12544){                                   // ---- tdec ----
    int pos0 = (B % 196) * 64;
    int ci0  = ((B / 196) & 7) * 64;
    int b    = B / 1568;
    #pragma unroll
    for (int i = 0; i < 4; i++){
      int idx = t + i * 256;
      int ci_l = idx >> 4, p4 = (idx & 15) * 4;
      const float4 f = *(const float4*)(dec + ((size_t)(b * 512 + ci0 + ci_l)) * 12544 + pos0 + p4);
      lt[(p4 + 0) * 80 + ci_l] = f2bf(f.x);
      lt[(p4 + 1) * 80 + ci_l] = f2bf(f.y);
      lt[(p4 + 2) * 80 + ci_l] = f2bf(f.z);
      lt[(p4 + 3) * 80 + ci_l] = f2bf(f.w);
    }
    __syncthreads();
    #pragma unroll
    for (int i = 0; i < 2; i++){
      int idx = t + i * 256;
      int p_l = idx >> 3, u = idx & 7;
      uint4 v = *(const uint4*)&lt[p_l * 80 + u * 8];
      *(uint4*)(decT + ((size_t)b * 12544 + pos0 + p_l) * 512 + ci0 + u * 8) = v;
    }
  } else if (B < 20736){                            // ---- wpe2 ----
    int id = (B - 12544) * 256 + t;
    if (id < 2097152){
      int co = id >> 12, rem = id & 4095;
      int ci8 = rem >> 6, pix = rem & 63;
      const float* s = pw + (size_t)co * 32768 + ci8 * 512 + pix;
      float v[8];
      #pragma unroll
      for (int j = 0; j < 8; j++) v[j] = s[j * 64];
      uint4 u; u.x = pk2(v[0], v[1]); u.y = pk2(v[2], v[3]);
      u.z = pk2(v[4], v[5]); u.w = pk2(v[6], v[7]);
      *(uint4*)(w2 + (size_t)co * 32768 + pix * 512 + ci8 * 8) = u;
    }
  } else if (B < 20864){ prep_cvt(mc_w, mcw, (B - 20736) * 256 + t, 32768); }
  else if (B < 20992){ prep_cvt(rc_w, rcw, (B - 20864) * 256 + t, 32768); }
  else if (B < 21120){ prep_tcvt(wq, wqT, (B - 20992) * 256 + t, 512, 512); }
  else if (B < 21312){ prep_tcvt(wk, wkT, (B - 21120) * 256 + t, 768, 512); }
  else if (B < 21504){ prep_tcvt(wv, wvT, (B - 21312) * 256 + t, 768, 512); }
  else if (B < 21632){ prep_tcvt(wo, woT, (B - 21504) * 256 + t, 512, 512); }
  else if (B < 22304){                              // ---- transb ----
    int id = (B - 21632) * 256 + t;
    if (id < 1792 * 96){
      int n = id / 96, e0 = (id - n * 96) * 8;
      int b = n / 224, nl = n - b * 224;
      uint4 u = {0u,0u,0u,0u};
      if (nl < 196){
        const float* sp = tr + ((size_t)(b * 196 + nl)) * 768 + e0;
        u.x = pk2(sp[0], sp[1]); u.y = pk2(sp[2], sp[3]);
        u.z = pk2(sp[4], sp[5]); u.w = pk2(sp[6], sp[7]);
      }
      *(uint4*)(transb + (size_t)n * 768 + e0) = u;
    }
  } else {                                          // ---- scales ----
    int i = (B - 22304) * 256 + t;
    if (i < 512){
      float sc1 = g1[i] / sqrtf(v1[i] + 1e-3f);
      s1[i] = sc1; o1[i] = (mcb[i] - m1[i]) * sc1 + b1[i];
      float sc2 = g2[i] / sqrtf(v2[i] + 1e-3f);
      s2[i] = sc2; o2[i] = (rcb[i] - m2[i]) * sc2 + b2[i];
    }
  }
}

// ---------- K1: patch-embed as split-K GEMM with partial buffers (round-5 best) ----------
__global__ void __launch_bounds__(256, 4) dra_k1(const uint16_t* __restrict__ decT,
    const uint16_t* __restrict__ wpe2, float* __restrict__ part)
{
  __shared__ uint16_t lA[128 * 32];
  __shared__ uint16_t lB[128 * 32];
  int t = threadIdx.x;
  int L = blockIdx.x;
  int x = L & 7, n = L >> 3;           // n in [0,112)
  int shi = n / 56, rem = n - shi * 56;
  int tok_t = rem >> 2, co_t = rem & 3;
  int s    = shi * 8 + x;              // split 0..15 pinned to xcd x
  int bco  = co_t * 128;
  int tok0 = tok_t * 128;
  int lane = t & 63, w = t >> 6;
  int wm = w >> 1, wn = w & 1;
  int lr = lane & 15, lg = lane >> 4;

  const uint16_t* aB[2]; const uint16_t* bB[2]; int uu[2];
  #pragma unroll
  for (int i = 0; i < 2; i++){
    int u = t + i * 256; uu[i] = u;
    int row = u >> 2, h = u & 3;
    int token = tok0 + row;
    int b = token / 224, tl = token - b * 224;
    if (tl > 195) tl = 195;                       // clamp pad tokens (finite garbage, unused later)
    int py = tl / 14, px = tl - py * 14;
    aB[i] = decT + ((size_t)b * 12544 + py * 896 + px * 8) * 512 + h * 8;
    bB[i] = wpe2 + (size_t)(bco + row) * 32768 + h * 8;
  }

  const v4f vzero = {0.f,0.f,0.f,0.f};
  v4f acc[4][4];
  #pragma unroll
  for (int i = 0; i < 4; i++)
    #pragma unroll
    for (int j = 0; j < 4; j++) acc[i][j] = vzero;

  for (int pix = s * 4; pix < s * 4 + 4; ++pix){
    int ky = pix >> 3, kx = pix & 7;
    int poff = (ky * 112 + kx) * 512;
    int k0p  = pix * 512;
    for (int ci0 = 0; ci0 < 512; ci0 += 32){
      gl16(aB[0] + poff + ci0, &lA[uu[0] * 8]);
      gl16(aB[1] + poff + ci0, &lA[uu[1] * 8]);
      gl16(bB[0] + k0p + ci0,  &lB[uu[0] * 8]);
      gl16(bB[1] + k0p + ci0,  &lB[uu[1] * 8]);
      __syncthreads();
      v8s av[4], bv[4];
      #pragma unroll
      for (int mf = 0; mf < 4; mf++) av[mf] = *(const v8s*)&lA[(wm*64 + mf*16 + lr) * 32 + lg * 8];
      #pragma unroll
      for (int nf = 0; nf < 4; nf++) bv[nf] = *(const v8s*)&lB[(wn*64 + nf*16 + lr) * 32 + lg * 8];
      #pragma unroll
      for (int mf = 0; mf < 4; mf++)
        #pragma unroll
        for (int nf = 0; nf < 4; nf++)
          acc[mf][nf] = __builtin_amdgcn_mfma_f32_16x16x32_bf16(av[mf], bv[nf], acc[mf][nf], 0, 0, 0);
      __syncthreads();
    }
  }
  float* pd = part + (size_t)s * 917504;
  #pragma unroll
  for (int mf = 0; mf < 4; mf++){
    #pragma unroll
    for (int nf = 0; nf < 4; nf++){
      int tokg = tok0 + wm*64 + mf*16 + lg*4;
      int cog  = bco  + wn*64 + nf*16 + lr;
      #pragma unroll
      for (int r = 0; r < 4; r++)
        pd[(size_t)(tokg + r) * 512 + cog] = acc[mf][nf][r];
    }
  }
}

// reduce 16 split partials + bias -> dlb bf16 [1792][512]
__global__ void __launch_bounds__(256) dra_red(const float* __restrict__ part,
    const float* __restrict__ peb, uint16_t* __restrict__ dlb){
  int id = blockIdx.x * 256 + threadIdx.x;
  if (id >= 114688) return;
  int tok = id >> 6, c8 = (id & 63) * 8;
  float a0=0,a1=0,a2=0,a3=0,a4=0,a5=0,a6=0,a7=0;
  #pragma unroll
  for (int s = 0; s < 16; s++){
    const float* p = part + (size_t)s * 917504 + (size_t)tok * 512 + c8;
    float4 x = *(const float4*)p, y = *(const float4*)(p + 4);
    a0 += x.x; a1 += x.y; a2 += x.z; a3 += x.w;
    a4 += y.x; a5 += y.y; a6 += y.z; a7 += y.w;
  }
  const float4 b0 = *(const float4*)(peb + c8), b1 = *(const float4*)(peb + c8 + 4);
  uint4 o; o.x = pk2(a0 + b0.x, a1 + b0.y); o.y = pk2(a2 + b0.z, a3 + b0.w);
  o.z = pk2(a4 + b1.x, a5 + b1.y); o.w = pk2(a6 + b1.z, a7 + b1.w);
  *(uint4*)(dlb + (size_t)tok * 512 + c8) = o;
}

// ---------- generic NT GEMM (attention chain): D[m][n] = sum_k A[m][k]*B[n][k] ----------
// BM = MREP*32, BN=64, BK=32, 256 threads (2x2 waves). Staging via global_load_lds with
// source-chunk swizzle c^((row>>1)&3): even rows cycle all 4 slots -> 2 lanes/bank (free).
template<int MREP>
__global__ void __launch_bounds__(256, 2) dra_gemm(
    const uint16_t* __restrict__ A, const uint16_t* __restrict__ Bn, void* __restrict__ Dv,
    int M, int N, int K, int lda, int ldb, int ldd,
    long long sAz, long long sBz, long long sDz,
    int epi, const float* __restrict__ svec, const float* __restrict__ ovec)
{
  constexpr int BM = MREP * 32;
  __shared__ uint16_t lA[BM * 32];
  __shared__ uint16_t lB[64 * 32];
  int t = threadIdx.x, z = blockIdx.z;
  int bm = blockIdx.x * BM, bn = blockIdx.y * 64;
  const uint16_t* Az = A + (size_t)z * sAz;
  const uint16_t* Bz = Bn + (size_t)z * sBz;
  int lane = t & 63, w = t >> 6;
  int wm = w >> 1, wn = w & 1;
  int lr = lane & 15, lg = lane >> 4;

  const uint16_t* aSrc[MREP/2]; int uuA[MREP/2];
  #pragma unroll
  for (int i = 0; i < MREP/2; i++){
    int u = t + i * 256; uuA[i] = u;
    int row = u >> 2, c = u & 3;
    int cs = c ^ ((row >> 1) & 3);
    int rg = bm + row; if (rg >= M) rg = M - 1;
    aSrc[i] = Az + (size_t)rg * lda + cs * 8;
  }
  const uint16_t* bSrc;
  {
    int row = t >> 2, c = t & 3;
    int cs = c ^ ((row >> 1) & 3);
    bSrc = Bz + (size_t)(bn + row) * ldb + cs * 8;
  }

  int aoff[MREP], boff[2];
  #pragma unroll
  for (int mf = 0; mf < MREP; mf++){
    int R = wm*(MREP*16) + mf*16 + lr;
    aoff[mf] = R * 32 + (lg ^ ((R >> 1) & 3)) * 8;
  }
  #pragma unroll
  for (int nf = 0; nf < 2; nf++){
    int R = wn*32 + nf*16 + lr;
    boff[nf] = R * 32 + (lg ^ ((R >> 1) & 3)) * 8;
  }

  const v4f vzero = {0.f, 0.f, 0.f, 0.f};
  v4f acc[MREP][2];
  #pragma unroll
  for (int i = 0; i < MREP; i++){ acc[i][0] = vzero; acc[i][1] = vzero; }

  for (int k0 = 0; k0 < K; k0 += 32){
    #pragma unroll
    for (int i = 0; i < MREP/2; i++)
      gl16(aSrc[i] + k0, &lA[uuA[i] * 8]);
    gl16(bSrc + k0, &lB[t * 8]);
    __syncthreads();
    v8s av[MREP], bv[2];
    #pragma unroll
    for (int mf = 0; mf < MREP; mf++) av[mf] = *(const v8s*)&lA[aoff[mf]];
    #pragma unroll
    for (int nf = 0; nf < 2; nf++)    bv[nf] = *(const v8s*)&lB[boff[nf]];
    #pragma unroll
    for (int mf = 0; mf < MREP; mf++)
      #pragma unroll
      for (int nf = 0; nf < 2; nf++)
        acc[mf][nf] = __builtin_amdgcn_mfma_f32_16x16x32_bf16(av[mf], bv[nf], acc[mf][nf], 0, 0, 0);
    __syncthreads();
  }

  #pragma unroll
  for (int mf = 0; mf < MREP; mf++){
    #pragma unroll
    for (int nf = 0; nf < 2; nf++){
      int mg0 = bm + wm*(MREP*16) + mf*16 + lg*4;
      int ng  = bn + wn*32 + nf*16 + lr;
      #pragma unroll
      for (int r = 0; r < 4; r++){
        int mg = mg0 + r;
        if (mg < M){
          float val = acc[mf][nf][r];
          size_t di = (size_t)z * sDz + (size_t)mg * ldd + ng;
          if (epi == 0)      ((float*)Dv)[di] = val;
          else if (epi == 1) ((uint16_t*)Dv)[di] = f2bf(val);
          else ((float*)Dv)[di] = fmaxf(val * svec[mg] + ovec[mg], 0.f);
        }
      }
    }
  }
}

// ---------- InstanceNorm stats: two-stage deterministic tree reduction ----------
__global__ void __launch_bounds__(256) dra_stats1(const float* __restrict__ sim,
                                                  double* __restrict__ ps){
  __shared__ double d1[256], d2[256];
  int b = blockIdx.y, blk = blockIdx.x, t = threadIdx.x;
  const float* s = sim + (size_t)b * 262144 + (size_t)blk * 2048 + t * 8;
  float4 x = *(const float4*)s, y = *(const float4*)(s + 4);
  double p1 = (double)x.x + x.y + x.z + x.w + y.x + y.y + y.z + y.w;
  double p2 = (double)x.x*x.x + (double)x.y*x.y + (double)x.z*x.z + (double)x.w*x.w
            + (double)y.x*y.x + (double)y.y*y.y + (double)y.z*y.z + (double)y.w*y.w;
  d1[t] = p1; d2[t] = p2;
  __syncthreads();
  for (int o = 128; o > 0; o >>= 1){
    if (t < o){ d1[t] += d1[t + o]; d2[t] += d2[t + o]; }
    __syncthreads();
  }
  if (t == 0){
    ps[(b * 128 + blk) * 2 + 0] = d1[0];
    ps[(b * 128 + blk) * 2 + 1] = d2[0];
  }
}

__global__ void __launch_bounds__(128) dra_stats2(const double* __restrict__ ps,
    const float* __restrict__ psig, const float* __restrict__ psib, float* __restrict__ ac){
  __shared__ double d1[128], d2[128];
  int b = blockIdx.x, t = threadIdx.x;
  d1[t] = ps[(b * 128 + t) * 2 + 0];
  d2[t] = ps[(b * 128 + t) * 2 + 1];
  __syncthreads();
  for (int o = 64; o > 0; o >>= 1){
    if (t < o){ d1[t] += d1[t + o]; d2[t] += d2[t + o]; }
    __syncthreads();
  }
  if (t == 0){
    double mean = d1[0] * (1.0 / 262144.0);
    double var  = d2[0] * (1.0 / 262144.0) - mean * mean;
    float a = psig[0] / (float)sqrt(var + 1e-3);
    ac[b * 2 + 0] = a;
    ac[b * 2 + 1] = psib[0] - (float)mean * a;
  }
}

// ---------- row softmax: P[b][s][t] bf16 ----------
__global__ void __launch_bounds__(256) dra_soft(const float* __restrict__ sim,
    const float* __restrict__ ac, uint16_t* __restrict__ P){
  int srow = blockIdx.x, b = blockIdx.y, t = threadIdx.x;
  const float* row = sim + (size_t)b * 262144 + (size_t)srow * 512;
  float a = ac[b * 2], c = ac[b * 2 + 1];
  float v0 = row[t] * a + c, v1 = row[t + 256] * a + c;
  __shared__ float red[256];
  red[t] = fmaxf(v0, v1);
  __syncthreads();
  for (int o = 128; o > 0; o >>= 1){
    if (t < o) red[t] = fmaxf(red[t], red[t + o]);
    __syncthreads();
  }
  float m = red[0];
  __syncthreads();
  float e0 = __expf(v0 - m), e1 = __expf(v1 - m);
  red[t] = e0 + e1;
  __syncthreads();
  for (int o = 128; o > 0; o >>= 1){
    if (t < o) red[t] += red[t + o];
    __syncthreads();
  }
  float inv = 1.f / red[0];
  uint16_t* pr = P + (size_t)b * 262144 + (size_t)srow * 512;
  pr[t] = f2bf(e0 * inv); pr[t + 256] = f2bf(e1 * inv);
}

// ---------- K3: mask conv + BN1 + ReLU, fused x recon-upsample -> out (round-5 best) ----------
__global__ void __launch_bounds__(256, 4) dra_k3(const uint16_t* __restrict__ decT,
    const uint16_t* __restrict__ mcw, const float* __restrict__ s1,
    const float* __restrict__ o1, const float* __restrict__ recon,
    float* __restrict__ outp)
{
  __shared__ uint16_t lA[128 * 32];
  __shared__ uint16_t lB[128 * 32];
  int t = threadIdx.x;
  int L = blockIdx.x;
  int x = L & 7, n = L >> 3;          // n in [0,392)
  int co_t = n & 3, pg = n >> 2;      // pg in [0,98)
  int p = pg * 8 + x;                 // pos-tile x batch, pinned to xcd x
  int bz = p / 98, pt = p - bz * 98;
  int bco  = co_t * 128;
  int pos0 = pt * 128;
  int lane = t & 63, w = t >> 6;
  int wm = w >> 1, wn = w & 1;
  int lr = lane & 15, lg = lane >> 4;

  const uint16_t* aB[2]; const uint16_t* bB[2]; int uu[2];
  #pragma unroll
  for (int i = 0; i < 2; i++){
    int u = t + i * 256; uu[i] = u;
    int row = u >> 2, h = u & 3;
    aB[i] = mcw  + (size_t)(bco + row) * 512 + h * 8;
    bB[i] = decT + ((size_t)bz * 12544 + pos0 + row) * 512 + h * 8;
  }

  const v4f vzero = {0.f,0.f,0.f,0.f};
  v4f acc[4][4];
  #pragma unroll
  for (int i = 0; i < 4; i++)
    #pragma unroll
    for (int j = 0; j < 4; j++) acc[i][j] = vzero;

  for (int k0 = 0; k0 < 512; k0 += 32){
    gl16(aB[0] + k0, &lA[uu[0] * 8]);
    gl16(aB[1] + k0, &lA[uu[1] * 8]);
    gl16(bB[0] + k0, &lB[uu[0] * 8]);
    gl16(bB[1] + k0, &lB[uu[1] * 8]);
    __syncthreads();
    v8s av[4], bv[4];
    #pragma unroll
    for (int mf = 0; mf < 4; mf++) av[mf] = *(const v8s*)&lA[(wm*64 + mf*16 + lr) * 32 + lg * 8];
    #pragma unroll
    for (int nf = 0; nf < 4; nf++) bv[nf] = *(const v8s*)&lB[(wn*64 + nf*16 + lr) * 32 + lg * 8];
    #pragma unroll
    for (int mf = 0; mf < 4; mf++)
      #pragma unroll
      for (int nf = 0; nf < 4; nf++)
        acc[mf][nf] = __builtin_amdgcn_mfma_f32_16x16x32_bf16(av[mf], bv[nf], acc[mf][nf], 0, 0, 0);
    __syncthreads();
  }

  #pragma unroll
  for (int mf = 0; mf < 4; mf++){
    #pragma unroll
    for (int r = 0; r < 4; r++){
      int co = bco + wm*64 + mf*16 + lg*4 + r;
      float sc = s1[co], of = o1[co];
      const float* rrow = recon + (size_t)co * 1792 + bz * 224;
      #pragma unroll
      for (int nf = 0; nf < 4; nf++){
        int pos = pos0 + wn*64 + nf*16 + lr;
        int h = pos / 112, wd = pos - h * 112;
        int pcol = (h >> 3) * 14 + (wd >> 3);
        float mask = fmaxf(acc[mf][nf][r] * sc + of, 0.f);
        outp[((size_t)(bz * 512 + co)) * 12544 + pos] = mask * rrow[pcol];
      }
    }
  }
}

// ---------- launch ----------
extern "C" void kernel_launch(void* const* d_in, const int* in_sizes, int n_in,
                              void* d_out, int out_size, void* d_ws, size_t ws_size,
                              hipStream_t stream) {
  (void)in_sizes; (void)n_in; (void)out_size; (void)ws_size;
  const float* dec   = (const float*)d_in[0];
  const float* trans = (const float*)d_in[1];
  const float* pe_w  = (const float*)d_in[2];
  const float* pe_b  = (const float*)d_in[3];
  const float* mc_w  = (const float*)d_in[4];
  const float* mc_b  = (const float*)d_in[5];
  const float* bn1g  = (const float*)d_in[6];
  const float* bn1b  = (const float*)d_in[7];
  const float* bn1m  = (const float*)d_in[8];
  const float* bn1v  = (const float*)d_in[9];
  const float* wq    = (const float*)d_in[10];
  const float* wk    = (const float*)d_in[11];
  const float* wv    = (const float*)d_in[12];
  const float* wo    = (const float*)d_in[13];
  const float* psig  = (const float*)d_in[14];
  const float* psib  = (const float*)d_in[15];
  const float* rc_w  = (const float*)d_in[16];
  const float* rc_b  = (const float*)d_in[17];
  const float* bn2g  = (const float*)d_in[18];
  const float* bn2b  = (const float*)d_in[19];
  const float* bn2m  = (const float*)d_in[20];
  const float* bn2v  = (const float*)d_in[21];

  char* p = (char*)d_ws;
  auto take = [&](size_t bytes) -> void* {
    void* r = (void*)p; p += (bytes + 255) & ~(size_t)255; return r;
  };
  uint16_t* decT   = (uint16_t*)take((size_t)8 * 12544 * 512 * 2);   // 102.8 MB
  uint16_t* wpe2   = (uint16_t*)take((size_t)512 * 32768 * 2);       // 33.5 MB
  uint16_t* mcw    = (uint16_t*)take((size_t)512 * 512 * 2);
  uint16_t* rcw    = (uint16_t*)take((size_t)512 * 512 * 2);
  uint16_t* wqT    = (uint16_t*)take((size_t)512 * 512 * 2);
  uint16_t* woT    = (uint16_t*)take((size_t)512 * 512 * 2);
  uint16_t* wkT    = (uint16_t*)take((size_t)512 * 768 * 2);
  uint16_t* wvT    = (uint16_t*)take((size_t)512 * 768 * 2);
  uint16_t* transb = (uint16_t*)take((size_t)1792 * 768 * 2);
  float*    s1v    = (float*)take(512 * 4);
  float*    o1v    = (float*)take(512 * 4);
  float*    s2v    = (float*)take(512 * 4);
  float*    o2v    = (float*)take(512 * 4);
  uint16_t* dlb    = (uint16_t*)take((size_t)1792 * 512 * 2);
  uint16_t* Qt     = (uint16_t*)take((size_t)512 * 1792 * 2);
  uint16_t* Kt     = (uint16_t*)take((size_t)512 * 1792 * 2);
  uint16_t* Vb     = (uint16_t*)take((size_t)1792 * 512 * 2);
  float*    ac     = (float*)take(256);
  double*   ps     = (double*)take((size_t)8 * 128 * 2 * 8);         // 16 KB stats partials
  float*    part   = (float*)take((size_t)16 * 1792 * 512 * 4);      // 58.7 MB
  // alias attention temps inside part (consumed by dra_red before these are written)
  float*    simb   = part;                                            // 8.39 MB
  uint16_t* P      = (uint16_t*)(part + 2097152);                     // 4.19 MB
  uint16_t* outb   = P + 2097152;                                     // 1.84 MB
  uint16_t* out2   = outb + 917504;                                   // 1.84 MB
  float*    recon  = (float*)(out2 + 917504);                         // 3.67 MB

  // fused prep (tdec + wpe2 + cvt x2 + tcvt x4 + transb + scales)
  dra_prep<<<22306, 256, 0, stream>>>(dec, decT, pe_w, wpe2, mc_w, mcw, rc_w, rcw,
      wq, wqT, wk, wkT, wv, wvT, wo, woT, trans, transb,
      mc_b, bn1g, bn1b, bn1m, bn1v, rc_b, bn2g, bn2b, bn2m, bn2v,
      s1v, o1v, s2v, o2v);

  // patch embedding: split-K partials + reduce (-> dlb bf16)
  dra_k1<<<896, 256, 0, stream>>>(decT, wpe2, part);
  dra_red<<<448, 256, 0, stream>>>(part, pe_b, dlb);

  // Qt[s][n] ; Kt[t][n] ; Vb[n][t]
  dra_gemm<2><<<dim3(8, 28, 1), 256, 0, stream>>>(wqT, dlb, Qt, 512, 1792, 512,
      512, 512, 1792, 0, 0, 0, 1, nullptr, nullptr);
  dra_gemm<2><<<dim3(8, 28, 1), 256, 0, stream>>>(wkT, transb, Kt, 512, 1792, 768,
      768, 768, 1792, 0, 0, 0, 1, nullptr, nullptr);
  dra_gemm<2><<<dim3(28, 8, 1), 256, 0, stream>>>(transb, wvT, Vb, 1792, 512, 768,
      768, 768, 512, 0, 0, 0, 1, nullptr, nullptr);

  // sim = Qt x Kt over padded tokens (zeros in pad cols of Kt)
  dra_gemm<2><<<dim3(8, 8, 8), 256, 0, stream>>>(Qt, Kt, simb, 512, 512, 224,
      1792, 1792, 512, 224, 224, 262144, 0, nullptr, nullptr);
  dra_stats1<<<dim3(128, 8), 256, 0, stream>>>(simb, ps);
  dra_stats2<<<8, 128, 0, stream>>>(ps, psig, psib, ac);
  dra_soft<<<dim3(512, 8), 256, 0, stream>>>(simb, ac, P);

  // out = P x V ; out2 = out x wo ; recon = relu(bn2(rc(out2)))
  dra_gemm<2><<<dim3(4, 8, 8), 256, 0, stream>>>(Vb, P, outb, 224, 512, 512,
      512, 512, 512, 114688, 262144, 114688, 1, nullptr, nullptr);
  dra_gemm<2><<<dim3(28, 8, 1), 256, 0, stream>>>(outb, woT, out2, 1792, 512, 512,
      512, 512, 512, 0, 0, 0, 1, nullptr, nullptr);
  dra_gemm<2><<<dim3(8, 28, 1), 256, 0, stream>>>(rcw, out2, recon, 512, 1792, 512,
      512, 512, 1792, 0, 0, 0, 2, s2v, o2v);

  // mask conv + BN1 + ReLU, x upsampled recon -> final output
  dra_k3<<<3136, 256, 0, stream>>>(decT, mcw, s1v, o1v, recon, (float*)d_out);
}